// Round 4
// baseline (550.428 us; speedup 1.0000x reference)
//
#include <hip/hip_runtime.h>
#include <hip/hip_bf16.h>

typedef __attribute__((ext_vector_type(4))) float f32x4;
typedef __attribute__((ext_vector_type(8))) short bf16x8;

typedef __attribute__((address_space(1))) unsigned int g_u32;
typedef __attribute__((address_space(3))) unsigned int l_u32;

__device__ __forceinline__ unsigned short f2bf(float f) {
  union { float f; unsigned int u; } v; v.f = f;
  unsigned int u = v.u;
  unsigned int r = (u + 0x7FFFu + ((u >> 16) & 1u)) >> 16;  // RNE
  return (unsigned short)r;
}

// ---------------- prep: pack W1(rows 4..260) and W2 into MFMA-frag order ----
// Bp[kb][n][j] = W[kb*8 + j][n]  (bf16): one lane's 8 k-elements are 16B contiguous.
__global__ void pack_w_kernel(const float* __restrict__ W1, const float* __restrict__ W2,
                              unsigned short* __restrict__ Bp1, unsigned short* __restrict__ Bp2) {
  int p = blockIdx.x * 256 + threadIdx.x;
  if (p < 32768) {                      // 256x128 for layer 1 (W1 rows 4..260)
    int j = p & 7, n = (p >> 3) & 127, kb = p >> 10;
    Bp1[p] = f2bf(W1[(4 + kb * 8 + j) * 128 + n]);
  } else if (p < 49152) {               // 128x128 for layer 2
    int q = p - 32768;
    int j = q & 7, n = (q >> 3) & 127, kb = q >> 10;
    Bp2[q] = f2bf(W2[(kb * 8 + j) * 128 + n]);
  }
}

// ---------------- prep: x fp32 -> bf16 ----------------
__global__ void convert_x_kernel(const float* __restrict__ x, unsigned short* __restrict__ xb, int n8) {
  int i = blockIdx.x * blockDim.x + threadIdx.x;
  if (i >= n8) return;
  const float4* s = (const float4*)x + (size_t)i * 2;
  float4 a = s[0], b = s[1];
  unsigned short h[8] = {f2bf(a.x), f2bf(a.y), f2bf(a.z), f2bf(a.w),
                         f2bf(b.x), f2bf(b.y), f2bf(b.z), f2bf(b.w)};
  int4 pk; __builtin_memcpy(&pk, h, 16);
  ((int4*)xb)[i] = pk;
}

constexpr int BM = 64;

// ---------------- persistent pipelined main kernel (bf16 gather path) ----------------
// grid = 768 (3 blocks/CU), grid-stride over 64-edge tiles. B1 frags persistent in
// VGPRs. Raw barriers with counted waits keep next-tile gather in flight across
// H-write + layer-2. Layer 2 computed TRANSPOSED (mfma(W2frag, Hfrag) -> out^T
// fragments) so each lane's 4 acc regs are 4 consecutive output features ->
// dwordx4 stores. Normal (cached) stores: L2 assembles full lines (NT regressed:
// partial-line write-through caused RMW, 2x WRITE + 5x FETCH in R3).
__global__ __launch_bounds__(256, 3)
void edge_persist(const unsigned short* __restrict__ xb,
                  const float* __restrict__ ea, const int* __restrict__ eidx,
                  const float* __restrict__ W1, const float* __restrict__ b1,
                  const float* __restrict__ b2,
                  const unsigned short* __restrict__ Bp1, const unsigned short* __restrict__ Bp2,
                  float* __restrict__ outp, int E, int ntiles) {
  __shared__ int4 AldsV[2048];   // 32 KB  A-tile [64 rows][256 k] bf16 (XOR-swizzled via source)
  __shared__ int4 HldsV[1024];   // 16 KB  h [64][128] bf16 (XOR-swizzled)
  __shared__ float ealds[2][256];

  char* Alds = (char*)AldsV;
  char* Hlds = (char*)HldsV;

  const int tid  = threadIdx.x;
  const int lane = tid & 63;
  const int wq   = lane >> 4;
  const int l16  = lane & 15;
  const int wave = tid >> 6;
  const int g    = tid & 15;
  const int s0   = tid >> 4;

  const int c0 = wave * 32 + l16;
  const int c1 = c0 + 16;

  // persistent scalars (layer-1 epilogue-init weights)
  const float bias0 = b1[c0], bias1 = b1[c1];
  const float w00 = W1[c0],       w01 = W1[128 + c0], w02 = W1[256 + c0], w03 = W1[384 + c0];
  const float w10 = W1[c1],       w11 = W1[128 + c1], w12 = W1[256 + c1], w13 = W1[384 + c1];

  // layer-2 bias: lane holds features ft*16 + wq*4 + {0..3}, ft = wave*2 + fi
  float4 b2v[2];
  #pragma unroll
  for (int fi = 0; fi < 2; ++fi)
    b2v[fi] = *(const float4*)(b2 + (wave * 2 + fi) * 16 + wq * 4);

  // persistent layer-1 B fragments (16 x int4 = 64 VGPR)
  bf16x8 bf1r[8][2];
  #pragma unroll
  for (int ks = 0; ks < 8; ++ks) {
    int kb = ks * 4 + wq;
    bf1r[ks][0] = __builtin_bit_cast(bf16x8, *(const int4*)(Bp1 + ((size_t)kb * 128 + c0) * 8));
    bf1r[ks][1] = __builtin_bit_cast(bf16x8, *(const int4*)(Bp1 + ((size_t)kb * 128 + c1) * 8));
  }

  int tile = blockIdx.x;
  if (tile >= ntiles) return;

  // ---- prologue: tile0 idx + ea + gather issue ----
  {
    int idx0[8];
    #pragma unroll
    for (int it = 0; it < 8; ++it) {
      int seg = it * 16 + s0;
      idx0[it] = eidx[(seg & 1) * E + tile * BM + (seg >> 1)];
    }
    ealds[0][tid] = ea[tile * 256 + tid];
    #pragma unroll
    for (int it = 0; it < 8; ++it) {
      int seg = it * 16 + s0;
      int r = seg >> 1;
      int gs = g ^ (r & 7);
      const unsigned short* src = xb + (size_t)idx0[it] * 128 + gs * 8;
      char* dstbase = Alds + (it * 16 + wave * 4) * 256;
      __builtin_amdgcn_global_load_lds((g_u32*)(void*)src, (l_u32*)(void*)dstbase, 16, 0, 0);
    }
  }

  int p = 0;
  for (; tile < ntiles; tile += gridDim.x) {
    const int nt_ = tile + gridDim.x;
    const int eb  = tile * BM;

    // TOP: this tile's gathers done; prev stores drained; ealds writes visible
    asm volatile("s_waitcnt vmcnt(0) lgkmcnt(0)" ::: "memory");
    __builtin_amdgcn_s_barrier();

    // prefetch next tile's idx + ea (latency hides under compute)
    int idxn[8];
    if (nt_ < ntiles) {
      #pragma unroll
      for (int it = 0; it < 8; ++it) {
        int seg = it * 16 + s0;
        idxn[it] = eidx[(seg & 1) * E + nt_ * BM + (seg >> 1)];
      }
      ealds[p ^ 1][tid] = ea[nt_ * 256 + tid];
    }

    // ---- layer 1 accumulator init: b1 + edge_attr x W1[0:4] in fp32 ----
    f32x4 acc[4][2];
    #pragma unroll
    for (int mf = 0; mf < 4; ++mf)
      #pragma unroll
      for (int rg = 0; rg < 4; ++rg) {
        int r = mf * 16 + wq * 4 + rg;
        float e0 = ealds[p][r * 4 + 0], e1 = ealds[p][r * 4 + 1];
        float e2 = ealds[p][r * 4 + 2], e3 = ealds[p][r * 4 + 3];
        acc[mf][0][rg] = bias0 + e0 * w00 + e1 * w01 + e2 * w02 + e3 * w03;
        acc[mf][1][rg] = bias1 + e0 * w10 + e1 * w11 + e2 * w12 + e3 * w13;
      }

    // ---- layer 1 MFMA: K = 256, B from persistent registers ----
    #pragma unroll
    for (int ks = 0; ks < 8; ++ks) {
      #pragma unroll
      for (int mf = 0; mf < 4; ++mf) {
        int r = mf * 16 + l16;
        int lofs = (r * 512 + ks * 64 + wq * 16) ^ ((r & 7) << 4);
        bf16x8 av = __builtin_bit_cast(bf16x8, *(const int4*)(Alds + lofs));
        acc[mf][0] = __builtin_amdgcn_mfma_f32_16x16x32_bf16(av, bf1r[ks][0], acc[mf][0], 0, 0, 0);
        acc[mf][1] = __builtin_amdgcn_mfma_f32_16x16x32_bf16(av, bf1r[ks][1], acc[mf][1], 0, 0, 0);
      }
    }

    // BAR2: all waves done reading A -> safe to overwrite with next gather
    asm volatile("s_waitcnt lgkmcnt(0)" ::: "memory");
    __builtin_amdgcn_s_barrier();

    // issue next tile's gather NOW; stays in flight across BAR3/layer-2/stores
    if (nt_ < ntiles) {
      #pragma unroll
      for (int it = 0; it < 8; ++it) {
        int seg = it * 16 + s0;
        int r = seg >> 1;
        int gs = g ^ (r & 7);
        const unsigned short* src = xb + (size_t)idxn[it] * 128 + gs * 8;
        char* dstbase = Alds + (it * 16 + wave * 4) * 256;
        __builtin_amdgcn_global_load_lds((g_u32*)(void*)src, (l_u32*)(void*)dstbase, 16, 0, 0);
      }
    }

    // layer-2 A fragments (W2, transposed use) per tile; latency hides under H-write
    bf16x8 bf2r[4][2];
    #pragma unroll
    for (int ks = 0; ks < 4; ++ks) {
      int kb = ks * 4 + wq;
      bf2r[ks][0] = __builtin_bit_cast(bf16x8, *(const int4*)(Bp2 + ((size_t)kb * 128 + (wave * 2 + 0) * 16 + l16) * 8));
      bf2r[ks][1] = __builtin_bit_cast(bf16x8, *(const int4*)(Bp2 + ((size_t)kb * 128 + (wave * 2 + 1) * 16 + l16) * 8));
    }

    // ---- ReLU + h -> LDS (bf16, swizzled) ----
    #pragma unroll
    for (int mf = 0; mf < 4; ++mf)
      #pragma unroll
      for (int nf = 0; nf < 2; ++nf) {
        int c = wave * 32 + nf * 16 + l16;
        #pragma unroll
        for (int rg = 0; rg < 4; ++rg) {
          int r = mf * 16 + wq * 4 + rg;
          float v = fmaxf(acc[mf][nf][rg], 0.0f);
          int lofs = (r * 256 + c * 2) ^ ((r & 7) << 4);
          *(unsigned short*)(Hlds + lofs) = f2bf(v);
        }
      }

    // BAR3: H visible (LDS only — gather stays in flight)
    asm volatile("s_waitcnt lgkmcnt(0)" ::: "memory");
    __builtin_amdgcn_s_barrier();

    // ---- layer 2 TRANSPOSED: D'[f][e] = sum_k W2[k][f] * H[e][k] ----
    // A-frag = W2 (from Bp2, lane row = f), B-frag = H row e (e = et*16 + l16).
    // D layout: col(lane&15) = e_local, row((lane>>4)*4+rg) = f_local -> lane's
    // 4 regs are 4 CONSECUTIVE features of one edge.
    f32x4 acc2[2][4];
    #pragma unroll
    for (int fi = 0; fi < 2; ++fi) {
      f32x4 bv = __builtin_bit_cast(f32x4, b2v[fi]);
      #pragma unroll
      for (int et = 0; et < 4; ++et) acc2[fi][et] = bv;
    }
    #pragma unroll
    for (int ks = 0; ks < 4; ++ks) {
      #pragma unroll
      for (int et = 0; et < 4; ++et) {
        int e = et * 16 + l16;
        int lofs = (e * 256 + ks * 64 + wq * 16) ^ ((e & 7) << 4);
        bf16x8 hv = __builtin_bit_cast(bf16x8, *(const int4*)(Hlds + lofs));
        acc2[0][et] = __builtin_amdgcn_mfma_f32_16x16x32_bf16(bf2r[ks][0], hv, acc2[0][et], 0, 0, 0);
        acc2[1][et] = __builtin_amdgcn_mfma_f32_16x16x32_bf16(bf2r[ks][1], hv, acc2[1][et], 0, 0, 0);
      }
    }

    // ---- epilogue: vectorized fp32 stores (normal/cached; dwordx4) ----
    #pragma unroll
    for (int fi = 0; fi < 2; ++fi)
      #pragma unroll
      for (int et = 0; et < 4; ++et) {
        size_t row = (size_t)(eb + et * 16 + l16);
        *(f32x4*)(outp + row * 128 + (wave * 2 + fi) * 16 + wq * 4) = acc2[fi][et];
      }

    p ^= 1;
  }
}

// ---------------- fallback (fp32 gather, non-persistent) for small ws ----------------
__global__ __launch_bounds__(256, 3)
void edge_main_f32(const float* __restrict__ xf,
                   const float* __restrict__ ea, const int* __restrict__ eidx,
                   const float* __restrict__ W1, const float* __restrict__ b1,
                   const float* __restrict__ b2,
                   const unsigned short* __restrict__ Bp1, const unsigned short* __restrict__ Bp2,
                   float* __restrict__ outp, int E) {
  __shared__ int4 AldsV[2048];
  __shared__ int4 HldsV[1024];
  __shared__ float ealds[256];
  char* Alds = (char*)AldsV;
  char* Hlds = (char*)HldsV;

  const int tid  = threadIdx.x;
  const int lane = tid & 63;
  const int wq   = lane >> 4;
  const int l16  = lane & 15;
  const int wave = tid >> 6;
  const int eb   = blockIdx.x * BM;

  ealds[tid] = ea[eb * 4 + tid];

  const int g  = tid & 15;
  const int s0 = tid >> 4;

  int idxv[8];
  #pragma unroll
  for (int it = 0; it < 8; ++it) {
    int seg = it * 16 + s0;
    idxv[it] = eidx[(seg & 1) * E + eb + (seg >> 1)];
  }

  const int c0 = wave * 32 + l16;
  const int c1 = c0 + 16;
  const float bias0 = b1[c0], bias1 = b1[c1];
  const float w00 = W1[c0],       w01 = W1[128 + c0], w02 = W1[256 + c0], w03 = W1[384 + c0];
  const float w10 = W1[c1],       w11 = W1[128 + c1], w12 = W1[256 + c1], w13 = W1[384 + c1];
  const float bias20 = b2[c0], bias21 = b2[c1];

  bf16x8 bf1r[8][2];
  #pragma unroll
  for (int ks = 0; ks < 8; ++ks) {
    int kb = ks * 4 + wq;
    bf1r[ks][0] = __builtin_bit_cast(bf16x8, *(const int4*)(Bp1 + ((size_t)kb * 128 + c0) * 8));
    bf1r[ks][1] = __builtin_bit_cast(bf16x8, *(const int4*)(Bp1 + ((size_t)kb * 128 + c1) * 8));
  }

  #pragma unroll
  for (int it = 0; it < 8; ++it) {
    int seg = it * 16 + s0;
    int r = seg >> 1, half = seg & 1;
    int lofs = (r * 512 + half * 256 + g * 16) ^ ((r & 7) << 4);
    const float* src = xf + (size_t)idxv[it] * 128 + g * 8;
    float4 a = *(const float4*)src;
    float4 c = *(const float4*)(src + 4);
    unsigned short h[8] = {f2bf(a.x), f2bf(a.y), f2bf(a.z), f2bf(a.w),
                           f2bf(c.x), f2bf(c.y), f2bf(c.z), f2bf(c.w)};
    int4 pk; __builtin_memcpy(&pk, h, 16);
    *(int4*)(Alds + lofs) = pk;
  }
  __syncthreads();

  f32x4 acc[4][2];
  #pragma unroll
  for (int mf = 0; mf < 4; ++mf)
    #pragma unroll
    for (int rg = 0; rg < 4; ++rg) {
      int r = mf * 16 + wq * 4 + rg;
      float e0 = ealds[r * 4 + 0], e1 = ealds[r * 4 + 1];
      float e2 = ealds[r * 4 + 2], e3 = ealds[r * 4 + 3];
      acc[mf][0][rg] = bias0 + e0 * w00 + e1 * w01 + e2 * w02 + e3 * w03;
      acc[mf][1][rg] = bias1 + e0 * w10 + e1 * w11 + e2 * w12 + e3 * w13;
    }

  #pragma unroll
  for (int ks = 0; ks < 8; ++ks)
    #pragma unroll
    for (int mf = 0; mf < 4; ++mf) {
      int r = mf * 16 + l16;
      int lofs = (r * 512 + ks * 64 + wq * 16) ^ ((r & 7) << 4);
      bf16x8 av = __builtin_bit_cast(bf16x8, *(const int4*)(Alds + lofs));
      acc[mf][0] = __builtin_amdgcn_mfma_f32_16x16x32_bf16(av, bf1r[ks][0], acc[mf][0], 0, 0, 0);
      acc[mf][1] = __builtin_amdgcn_mfma_f32_16x16x32_bf16(av, bf1r[ks][1], acc[mf][1], 0, 0, 0);
    }

  bf16x8 bf2r[4][2];
  #pragma unroll
  for (int ks = 0; ks < 4; ++ks) {
    int kb = ks * 4 + wq;
    bf2r[ks][0] = __builtin_bit_cast(bf16x8, *(const int4*)(Bp2 + ((size_t)kb * 128 + c0) * 8));
    bf2r[ks][1] = __builtin_bit_cast(bf16x8, *(const int4*)(Bp2 + ((size_t)kb * 128 + c1) * 8));
  }

  #pragma unroll
  for (int mf = 0; mf < 4; ++mf)
    #pragma unroll
    for (int nf = 0; nf < 2; ++nf) {
      int c = wave * 32 + nf * 16 + l16;
      #pragma unroll
      for (int rg = 0; rg < 4; ++rg) {
        int r = mf * 16 + wq * 4 + rg;
        float v = fmaxf(acc[mf][nf][rg], 0.0f);
        int lofs = (r * 256 + c * 2) ^ ((r & 7) << 4);
        *(unsigned short*)(Hlds + lofs) = f2bf(v);
      }
    }
  __syncthreads();

  f32x4 acc2[4][2];
  #pragma unroll
  for (int mf = 0; mf < 4; ++mf) {
    acc2[mf][0] = (f32x4){bias20, bias20, bias20, bias20};
    acc2[mf][1] = (f32x4){bias21, bias21, bias21, bias21};
  }
  #pragma unroll
  for (int ks = 0; ks < 4; ++ks)
    #pragma unroll
    for (int mf = 0; mf < 4; ++mf) {
      int r = mf * 16 + l16;
      int lofs = (r * 256 + ks * 64 + wq * 16) ^ ((r & 7) << 4);
      bf16x8 av = __builtin_bit_cast(bf16x8, *(const int4*)(Hlds + lofs));
      acc2[mf][0] = __builtin_amdgcn_mfma_f32_16x16x32_bf16(av, bf2r[ks][0], acc2[mf][0], 0, 0, 0);
      acc2[mf][1] = __builtin_amdgcn_mfma_f32_16x16x32_bf16(av, bf2r[ks][1], acc2[mf][1], 0, 0, 0);
    }

  #pragma unroll
  for (int mf = 0; mf < 4; ++mf)
    #pragma unroll
    for (int nf = 0; nf < 2; ++nf) {
      int c = wave * 32 + nf * 16 + l16;
      #pragma unroll
      for (int rg = 0; rg < 4; ++rg) {
        int r = mf * 16 + wq * 4 + rg;
        outp[(size_t)(eb + r) * 128 + c] = acc2[mf][nf][rg];
      }
    }
}

extern "C" void kernel_launch(void* const* d_in, const int* in_sizes, int n_in,
                              void* d_out, int out_size, void* d_ws, size_t ws_size,
                              hipStream_t stream) {
  const float* x  = (const float*)d_in[0];
  const float* ea = (const float*)d_in[1];
  const int* eidx = (const int*)d_in[2];
  const float* W1 = (const float*)d_in[3];
  const float* b1 = (const float*)d_in[4];
  const float* W2 = (const float*)d_in[5];
  const float* b2 = (const float*)d_in[6];
  float* outp = (float*)d_out;

  const int E = in_sizes[2] / 2;
  const int nnodes = in_sizes[0] / 128;
  const int ntiles = E / BM;

  unsigned short* Bp1 = (unsigned short*)d_ws;           // 64 KB
  unsigned short* Bp2 = Bp1 + 32768;                     // 32 KB
  unsigned short* xb  = (unsigned short*)((char*)d_ws + 98304);
  const size_t need = 98304 + (size_t)nnodes * 128 * 2;

  pack_w_kernel<<<192, 256, 0, stream>>>(W1, W2, Bp1, Bp2);

  if (ws_size >= need) {
    int n8 = nnodes * 128 / 8;
    convert_x_kernel<<<(n8 + 255) / 256, 256, 0, stream>>>(x, xb, n8);
    int nblk = 768;                       // 3 blocks/CU x 256 CU
    if (nblk > ntiles) nblk = ntiles;
    edge_persist<<<nblk, 256, 0, stream>>>(xb, ea, eidx, W1, b1, b2, Bp1, Bp2, outp, E, ntiles);
  } else {
    edge_main_f32<<<ntiles, 256, 0, stream>>>(x, ea, eidx, W1, b1, b2, Bp1, Bp2, outp, E);
  }
}

// Round 5
// 252.188 us; speedup vs baseline: 2.1826x; 2.1826x over previous
//
#include <hip/hip_runtime.h>
#include <hip/hip_bf16.h>

typedef __attribute__((ext_vector_type(4))) float f32x4;
typedef __attribute__((ext_vector_type(8))) short bf16x8;

typedef __attribute__((address_space(1))) unsigned int g_u32;
typedef __attribute__((address_space(3))) unsigned int l_u32;

__device__ __forceinline__ unsigned short f2bf(float f) {
  union { float f; unsigned int u; } v; v.f = f;
  unsigned int u = v.u;
  unsigned int r = (u + 0x7FFFu + ((u >> 16) & 1u)) >> 16;  // RNE
  return (unsigned short)r;
}

// ---------------- prep: pack W1(rows 4..260) and W2 into MFMA-frag order ----
// Bp[kb][n][j] = W[kb*8 + j][n]  (bf16): one lane's 8 k-elements are 16B contiguous.
__global__ void pack_w_kernel(const float* __restrict__ W1, const float* __restrict__ W2,
                              unsigned short* __restrict__ Bp1, unsigned short* __restrict__ Bp2) {
  int p = blockIdx.x * 256 + threadIdx.x;
  if (p < 32768) {                      // 256x128 for layer 1 (W1 rows 4..260)
    int j = p & 7, n = (p >> 3) & 127, kb = p >> 10;
    Bp1[p] = f2bf(W1[(4 + kb * 8 + j) * 128 + n]);
  } else if (p < 49152) {               // 128x128 for layer 2
    int q = p - 32768;
    int j = q & 7, n = (q >> 3) & 127, kb = q >> 10;
    Bp2[q] = f2bf(W2[(kb * 8 + j) * 128 + n]);
  }
}

// ---------------- prep: x fp32 -> bf16 ----------------
__global__ void convert_x_kernel(const float* __restrict__ x, unsigned short* __restrict__ xb, int n8) {
  int i = blockIdx.x * blockDim.x + threadIdx.x;
  if (i >= n8) return;
  const float4* s = (const float4*)x + (size_t)i * 2;
  float4 a = s[0], b = s[1];
  unsigned short h[8] = {f2bf(a.x), f2bf(a.y), f2bf(a.z), f2bf(a.w),
                         f2bf(b.x), f2bf(b.y), f2bf(b.z), f2bf(b.w)};
  int4 pk; __builtin_memcpy(&pk, h, 16);
  ((int4*)xb)[i] = pk;
}

constexpr int BM = 64;

// ---------------- main fused kernel: one 64-edge tile per block ----------------
// NON-persistent (persistent grid caused 1.84x write + 5x fetch amplification via
// desynced partial-line eviction / L3 thrash in R3/R4 — reverted to the clean-traffic
// R2 shape). Both layers computed TRANSPOSED: D = [features][edges], so each lane's
// 4 acc regs are 4 consecutive features of one edge -> packed b64 H-writes and
// dwordx4 output stores. H overlays the dead A-tile after layer-1 (extra barrier),
// LDS = 33 KB -> 4 blocks/CU (16 waves).
__global__ __launch_bounds__(256, 4)
void edge_tile(const unsigned short* __restrict__ xb,
               const float* __restrict__ ea, const int* __restrict__ eidx,
               const float* __restrict__ W1, const float* __restrict__ b1,
               const float* __restrict__ b2,
               const unsigned short* __restrict__ Bp1, const unsigned short* __restrict__ Bp2,
               float* __restrict__ outp, int E) {
  __shared__ int4 AldsV[2048];   // 32 KB: A-tile [64 rows][256 k] bf16; H overlays first 16 KB
  __shared__ float ealds[256];   // 64 edges x 4 attrs

  char* Alds = (char*)AldsV;

  const int tid  = threadIdx.x;
  const int lane = tid & 63;
  const int wq   = lane >> 4;
  const int l16  = lane & 15;
  const int wave = tid >> 6;
  const int g    = tid & 15;
  const int s0   = tid >> 4;
  const int eb   = blockIdx.x * BM;

  // ---- issue independent loads first ----
  ealds[tid] = ea[eb * 4 + tid];

  int idxv[8];
  #pragma unroll
  for (int it = 0; it < 8; ++it) {
    int seg = it * 16 + s0;
    idxv[it] = eidx[(seg & 1) * E + eb + (seg >> 1)];
  }

  // lane's feature block: f = wave*32 + fi*16 + wq*4 + {0..3}
  const int f_lo0 = wave * 32 + wq * 4;        // fi = 0
  // hoisted vector scalars (latency hides under gather)
  f32x4 b1v[2], b2v[2], w1v[2][4];
  #pragma unroll
  for (int fi = 0; fi < 2; ++fi) {
    int f = f_lo0 + fi * 16;
    b1v[fi] = *(const f32x4*)(b1 + f);
    b2v[fi] = *(const f32x4*)(b2 + f);
    #pragma unroll
    for (int j = 0; j < 4; ++j)
      w1v[fi][j] = *(const f32x4*)(W1 + j * 128 + f);
  }

  // hoisted layer-1 W-fragments (A-operand): lane row = wave*32 + fi*16 + l16
  bf16x8 bf1r[8][2];
  #pragma unroll
  for (int ks = 0; ks < 8; ++ks) {
    int kb = ks * 4 + wq;
    #pragma unroll
    for (int fi = 0; fi < 2; ++fi) {
      int n = wave * 32 + fi * 16 + l16;
      bf1r[ks][fi] = __builtin_bit_cast(bf16x8, *(const int4*)(Bp1 + ((size_t)kb * 128 + n) * 8));
    }
  }

  // ---- gather: async global->LDS, linear dest, pre-swizzled source ----
  #pragma unroll
  for (int it = 0; it < 8; ++it) {
    int seg = it * 16 + s0;
    int r = seg >> 1;
    int gs = g ^ (r & 7);
    const unsigned short* src = xb + (size_t)idxv[it] * 128 + gs * 8;
    char* dstbase = Alds + (it * 16 + wave * 4) * 256;
    __builtin_amdgcn_global_load_lds((g_u32*)(void*)src, (l_u32*)(void*)dstbase, 16, 0, 0);
  }
  __syncthreads();

  // ---- layer 1 acc init: acc[fi][et] (f32x4 over rg) = b1 + ea[e]x W1[0:4] ----
  f32x4 acc[2][4];
  #pragma unroll
  for (int fi = 0; fi < 2; ++fi)
    #pragma unroll
    for (int et = 0; et < 4; ++et) {
      int e = et * 16 + l16;
      float e0 = ealds[e * 4 + 0], e1 = ealds[e * 4 + 1];
      float e2 = ealds[e * 4 + 2], e3 = ealds[e * 4 + 3];
      acc[fi][et] = b1v[fi] + e0 * w1v[fi][0] + e1 * w1v[fi][1]
                            + e2 * w1v[fi][2] + e3 * w1v[fi][3];
    }

  // ---- layer 1 MFMA (transposed): D[f][e] = sum_k W1[k][f] * Aedge[e][k] ----
  #pragma unroll
  for (int ks = 0; ks < 8; ++ks) {
    #pragma unroll
    for (int et = 0; et < 4; ++et) {
      int e = et * 16 + l16;
      int lofs = (e * 512 + ks * 64 + wq * 16) ^ ((e & 7) << 4);
      bf16x8 av = __builtin_bit_cast(bf16x8, *(const int4*)(Alds + lofs));
      acc[0][et] = __builtin_amdgcn_mfma_f32_16x16x32_bf16(bf1r[ks][0], av, acc[0][et], 0, 0, 0);
      acc[1][et] = __builtin_amdgcn_mfma_f32_16x16x32_bf16(bf1r[ks][1], av, acc[1][et], 0, 0, 0);
    }
  }

  // layer-2 W-fragments: issue before barrier, latency hides under it
  bf16x8 bf2r[4][2];
  #pragma unroll
  for (int ks = 0; ks < 4; ++ks) {
    int kb = ks * 4 + wq;
    #pragma unroll
    for (int fi = 0; fi < 2; ++fi) {
      int n = wave * 32 + fi * 16 + l16;
      bf2r[ks][fi] = __builtin_bit_cast(bf16x8, *(const int4*)(Bp2 + ((size_t)kb * 128 + n) * 8));
    }
  }

  // BAR2: all waves done reading A-tile -> safe to overlay H
  __syncthreads();

  // ---- ReLU + H -> LDS (packed 4x bf16 = b64 writes), H[e][128] bf16 swizzled ----
  #pragma unroll
  for (int fi = 0; fi < 2; ++fi)
    #pragma unroll
    for (int et = 0; et < 4; ++et) {
      int e = et * 16 + l16;
      float v0 = fmaxf(acc[fi][et][0], 0.0f);
      float v1 = fmaxf(acc[fi][et][1], 0.0f);
      float v2 = fmaxf(acc[fi][et][2], 0.0f);
      float v3 = fmaxf(acc[fi][et][3], 0.0f);
      uint2 pk;
      pk.x = (unsigned int)f2bf(v0) | ((unsigned int)f2bf(v1) << 16);
      pk.y = (unsigned int)f2bf(v2) | ((unsigned int)f2bf(v3) << 16);
      int ho = (e * 256 + (wave * 32 + fi * 16 + wq * 4) * 2) ^ ((e & 7) << 4);
      *(uint2*)(Alds + ho) = pk;
    }

  // BAR3: H visible
  __syncthreads();

  // ---- layer 2 (transposed): D[f][e] = sum_k W2[k][f] * H[e][k] ----
  f32x4 acc2[2][4];
  #pragma unroll
  for (int fi = 0; fi < 2; ++fi)
    #pragma unroll
    for (int et = 0; et < 4; ++et)
      acc2[fi][et] = b2v[fi];
  #pragma unroll
  for (int ks = 0; ks < 4; ++ks) {
    #pragma unroll
    for (int et = 0; et < 4; ++et) {
      int e = et * 16 + l16;
      int lofs = (e * 256 + ks * 64 + wq * 16) ^ ((e & 7) << 4);
      bf16x8 hv = __builtin_bit_cast(bf16x8, *(const int4*)(Alds + lofs));
      acc2[0][et] = __builtin_amdgcn_mfma_f32_16x16x32_bf16(bf2r[ks][0], hv, acc2[0][et], 0, 0, 0);
      acc2[1][et] = __builtin_amdgcn_mfma_f32_16x16x32_bf16(bf2r[ks][1], hv, acc2[1][et], 0, 0, 0);
    }
  }

  // ---- epilogue: dwordx4 cached stores (4 consecutive features per lane) ----
  #pragma unroll
  for (int fi = 0; fi < 2; ++fi)
    #pragma unroll
    for (int et = 0; et < 4; ++et) {
      size_t row = (size_t)(eb + et * 16 + l16);
      *(f32x4*)(outp + row * 128 + wave * 32 + fi * 16 + wq * 4) = acc2[fi][et];
    }
}

// ---------------- fallback (fp32 gather, layer layouts as verified in R1/R2) ----
__global__ __launch_bounds__(256, 3)
void edge_main_f32(const float* __restrict__ xf,
                   const float* __restrict__ ea, const int* __restrict__ eidx,
                   const float* __restrict__ W1, const float* __restrict__ b1,
                   const float* __restrict__ b2,
                   const unsigned short* __restrict__ Bp1, const unsigned short* __restrict__ Bp2,
                   float* __restrict__ outp, int E) {
  __shared__ int4 AldsV[2048];
  __shared__ int4 HldsV[1024];
  __shared__ float ealds[256];
  char* Alds = (char*)AldsV;
  char* Hlds = (char*)HldsV;

  const int tid  = threadIdx.x;
  const int lane = tid & 63;
  const int wq   = lane >> 4;
  const int l16  = lane & 15;
  const int wave = tid >> 6;
  const int eb   = blockIdx.x * BM;

  ealds[tid] = ea[eb * 4 + tid];

  const int g  = tid & 15;
  const int s0 = tid >> 4;

  int idxv[8];
  #pragma unroll
  for (int it = 0; it < 8; ++it) {
    int seg = it * 16 + s0;
    idxv[it] = eidx[(seg & 1) * E + eb + (seg >> 1)];
  }

  const int c0 = wave * 32 + l16;
  const int c1 = c0 + 16;
  const float bias0 = b1[c0], bias1 = b1[c1];
  const float w00 = W1[c0],       w01 = W1[128 + c0], w02 = W1[256 + c0], w03 = W1[384 + c0];
  const float w10 = W1[c1],       w11 = W1[128 + c1], w12 = W1[256 + c1], w13 = W1[384 + c1];
  const float bias20 = b2[c0], bias21 = b2[c1];

  bf16x8 bf1r[8][2];
  #pragma unroll
  for (int ks = 0; ks < 8; ++ks) {
    int kb = ks * 4 + wq;
    bf1r[ks][0] = __builtin_bit_cast(bf16x8, *(const int4*)(Bp1 + ((size_t)kb * 128 + c0) * 8));
    bf1r[ks][1] = __builtin_bit_cast(bf16x8, *(const int4*)(Bp1 + ((size_t)kb * 128 + c1) * 8));
  }

  #pragma unroll
  for (int it = 0; it < 8; ++it) {
    int seg = it * 16 + s0;
    int r = seg >> 1, half = seg & 1;
    int lofs = (r * 512 + half * 256 + g * 16) ^ ((r & 7) << 4);
    const float* src = xf + (size_t)idxv[it] * 128 + g * 8;
    float4 a = *(const float4*)src;
    float4 c = *(const float4*)(src + 4);
    unsigned short h[8] = {f2bf(a.x), f2bf(a.y), f2bf(a.z), f2bf(a.w),
                           f2bf(c.x), f2bf(c.y), f2bf(c.z), f2bf(c.w)};
    int4 pk; __builtin_memcpy(&pk, h, 16);
    *(int4*)(Alds + lofs) = pk;
  }
  __syncthreads();

  f32x4 acc[4][2];
  #pragma unroll
  for (int mf = 0; mf < 4; ++mf)
    #pragma unroll
    for (int rg = 0; rg < 4; ++rg) {
      int r = mf * 16 + wq * 4 + rg;
      float e0 = ealds[r * 4 + 0], e1 = ealds[r * 4 + 1];
      float e2 = ealds[r * 4 + 2], e3 = ealds[r * 4 + 3];
      acc[mf][0][rg] = bias0 + e0 * w00 + e1 * w01 + e2 * w02 + e3 * w03;
      acc[mf][1][rg] = bias1 + e0 * w10 + e1 * w11 + e2 * w12 + e3 * w13;
    }

  #pragma unroll
  for (int ks = 0; ks < 8; ++ks)
    #pragma unroll
    for (int mf = 0; mf < 4; ++mf) {
      int r = mf * 16 + l16;
      int lofs = (r * 512 + ks * 64 + wq * 16) ^ ((r & 7) << 4);
      bf16x8 av = __builtin_bit_cast(bf16x8, *(const int4*)(Alds + lofs));
      acc[mf][0] = __builtin_amdgcn_mfma_f32_16x16x32_bf16(av, bf1r[ks][0], acc[mf][0], 0, 0, 0);
      acc[mf][1] = __builtin_amdgcn_mfma_f32_16x16x32_bf16(av, bf1r[ks][1], acc[mf][1], 0, 0, 0);
    }

  bf16x8 bf2r[4][2];
  #pragma unroll
  for (int ks = 0; ks < 4; ++ks) {
    int kb = ks * 4 + wq;
    bf2r[ks][0] = __builtin_bit_cast(bf16x8, *(const int4*)(Bp2 + ((size_t)kb * 128 + c0) * 8));
    bf2r[ks][1] = __builtin_bit_cast(bf16x8, *(const int4*)(Bp2 + ((size_t)kb * 128 + c1) * 8));
  }

  #pragma unroll
  for (int mf = 0; mf < 4; ++mf)
    #pragma unroll
    for (int nf = 0; nf < 2; ++nf) {
      int c = wave * 32 + nf * 16 + l16;
      #pragma unroll
      for (int rg = 0; rg < 4; ++rg) {
        int r = mf * 16 + wq * 4 + rg;
        float v = fmaxf(acc[mf][nf][rg], 0.0f);
        int lofs = (r * 256 + c * 2) ^ ((r & 7) << 4);
        *(unsigned short*)(Hlds + lofs) = f2bf(v);
      }
    }
  __syncthreads();

  f32x4 acc2[4][2];
  #pragma unroll
  for (int mf = 0; mf < 4; ++mf) {
    acc2[mf][0] = (f32x4){bias20, bias20, bias20, bias20};
    acc2[mf][1] = (f32x4){bias21, bias21, bias21, bias21};
  }
  #pragma unroll
  for (int ks = 0; ks < 4; ++ks)
    #pragma unroll
    for (int mf = 0; mf < 4; ++mf) {
      int r = mf * 16 + l16;
      int lofs = (r * 256 + ks * 64 + wq * 16) ^ ((r & 7) << 4);
      bf16x8 av = __builtin_bit_cast(bf16x8, *(const int4*)(Hlds + lofs));
      acc2[mf][0] = __builtin_amdgcn_mfma_f32_16x16x32_bf16(av, bf2r[ks][0], acc2[mf][0], 0, 0, 0);
      acc2[mf][1] = __builtin_amdgcn_mfma_f32_16x16x32_bf16(av, bf2r[ks][1], acc2[mf][1], 0, 0, 0);
    }

  #pragma unroll
  for (int mf = 0; mf < 4; ++mf)
    #pragma unroll
    for (int nf = 0; nf < 2; ++nf) {
      int c = wave * 32 + nf * 16 + l16;
      #pragma unroll
      for (int rg = 0; rg < 4; ++rg) {
        int r = mf * 16 + wq * 4 + rg;
        outp[(size_t)(eb + r) * 128 + c] = acc2[mf][nf][rg];
      }
    }
}

extern "C" void kernel_launch(void* const* d_in, const int* in_sizes, int n_in,
                              void* d_out, int out_size, void* d_ws, size_t ws_size,
                              hipStream_t stream) {
  const float* x  = (const float*)d_in[0];
  const float* ea = (const float*)d_in[1];
  const int* eidx = (const int*)d_in[2];
  const float* W1 = (const float*)d_in[3];
  const float* b1 = (const float*)d_in[4];
  const float* W2 = (const float*)d_in[5];
  const float* b2 = (const float*)d_in[6];
  float* outp = (float*)d_out;

  const int E = in_sizes[2] / 2;
  const int nnodes = in_sizes[0] / 128;
  const int ntiles = E / BM;

  unsigned short* Bp1 = (unsigned short*)d_ws;           // 64 KB
  unsigned short* Bp2 = Bp1 + 32768;                     // 32 KB
  unsigned short* xb  = (unsigned short*)((char*)d_ws + 98304);
  const size_t need = 98304 + (size_t)nnodes * 128 * 2;

  pack_w_kernel<<<192, 256, 0, stream>>>(W1, W2, Bp1, Bp2);

  if (ws_size >= need) {
    int n8 = nnodes * 128 / 8;
    convert_x_kernel<<<(n8 + 255) / 256, 256, 0, stream>>>(x, xb, n8);
    edge_tile<<<ntiles, 256, 0, stream>>>(xb, ea, eidx, W1, b1, b2, Bp1, Bp2, outp, E);
  } else {
    edge_main_f32<<<ntiles, 256, 0, stream>>>(x, ea, eidx, W1, b1, b2, Bp1, Bp2, outp, E);
  }
}

// Round 6
// 244.147 us; speedup vs baseline: 2.2545x; 1.0329x over previous
//
#include <hip/hip_runtime.h>
#include <hip/hip_bf16.h>

typedef __attribute__((ext_vector_type(4))) float f32x4;
typedef __attribute__((ext_vector_type(8))) short bf16x8;

typedef __attribute__((address_space(1))) unsigned int g_u32;
typedef __attribute__((address_space(3))) unsigned int l_u32;

__device__ __forceinline__ unsigned short f2bf(float f) {
  union { float f; unsigned int u; } v; v.f = f;
  unsigned int u = v.u;
  unsigned int r = (u + 0x7FFFu + ((u >> 16) & 1u)) >> 16;  // RNE
  return (unsigned short)r;
}

// ---------------- prep: pack W1(rows 4..260) and W2 into MFMA-B fragment order ----
// Bp[kb][n][j] = W[kb*8 + j][n]  (bf16): one lane's 8 k-elements are 16B contiguous.
__global__ void pack_w_kernel(const float* __restrict__ W1, const float* __restrict__ W2,
                              unsigned short* __restrict__ Bp1, unsigned short* __restrict__ Bp2) {
  int p = blockIdx.x * 256 + threadIdx.x;
  if (p < 32768) {                      // 256x128 for layer 1 (W1 rows 4..260)
    int j = p & 7, n = (p >> 3) & 127, kb = p >> 10;
    Bp1[p] = f2bf(W1[(4 + kb * 8 + j) * 128 + n]);
  } else if (p < 49152) {               // 128x128 for layer 2
    int q = p - 32768;
    int j = q & 7, n = (q >> 3) & 127, kb = q >> 10;
    Bp2[q] = f2bf(W2[(kb * 8 + j) * 128 + n]);
  }
}

// ---------------- prep: x fp32 -> bf16 ----------------
__global__ void convert_x_kernel(const float* __restrict__ x, unsigned short* __restrict__ xb, int n8) {
  int i = blockIdx.x * blockDim.x + threadIdx.x;
  if (i >= n8) return;
  const float4* s = (const float4*)x + (size_t)i * 2;
  float4 a = s[0], b = s[1];
  unsigned short h[8] = {f2bf(a.x), f2bf(a.y), f2bf(a.z), f2bf(a.w),
                         f2bf(b.x), f2bf(b.y), f2bf(b.z), f2bf(b.w)};
  int4 pk; __builtin_memcpy(&pk, h, 16);
  ((int4*)xb)[i] = pk;
}

constexpr int BM = 64;

// ---------------- main fused kernel: one 64-edge tile per block ----------------
// R2 structure verbatim (best measured: clean 320 MB write / 157 MB fetch) with ONE
// change: H overlays the dead A-tile (extra barrier) -> LDS 49->33 KB -> 4 blocks/CU.
// Epilogue stays NON-transposed scalar: consecutive lanes (l16) write consecutive
// dwords of a row — the verified-clean store geometry. (Transposed epilogues with
// lane-stride-16 row segments doubled WRITE_SIZE in R4/R5; persistence amplified
// fetch in R3/R4. Both abandoned.)
__global__ __launch_bounds__(256, 4)
void edge_tile2(const unsigned short* __restrict__ xb,
                const float* __restrict__ ea, const int* __restrict__ eidx,
                const float* __restrict__ W1, const float* __restrict__ b1,
                const float* __restrict__ b2,
                const unsigned short* __restrict__ Bp1, const unsigned short* __restrict__ Bp2,
                float* __restrict__ outp, int E) {
  __shared__ int4 AldsV[2048];   // 32 KB: A-tile [64 rows][256 k] bf16; H overlays first 16 KB
  __shared__ float ealds[256];   // 64 edges x 4 attrs

  char* Alds = (char*)AldsV;
  char* Hlds = (char*)AldsV;     // overlay (valid after BAR2)

  const int tid  = threadIdx.x;
  const int lane = tid & 63;
  const int wq   = lane >> 4;
  const int l16  = lane & 15;
  const int wave = tid >> 6;
  const int g    = tid & 15;
  const int s0   = tid >> 4;
  const int eb   = blockIdx.x * BM;

  // ---- issue independent loads first: edge_attr, eidx prefetch ----
  ealds[tid] = ea[eb * 4 + tid];

  int idxv[8];
  #pragma unroll
  for (int it = 0; it < 8; ++it) {
    int seg = it * 16 + s0;
    idxv[it] = eidx[(seg & 1) * E + eb + (seg >> 1)];
  }

  const int c0 = wave * 32 + l16;
  const int c1 = c0 + 16;

  // ---- hoisted epilogue/init scalars (latency hides under gather) ----
  const float bias0 = b1[c0], bias1 = b1[c1];
  const float w00 = W1[c0],       w01 = W1[128 + c0], w02 = W1[256 + c0], w03 = W1[384 + c0];
  const float w10 = W1[c1],       w11 = W1[128 + c1], w12 = W1[256 + c1], w13 = W1[384 + c1];
  const float bias20 = b2[c0], bias21 = b2[c1];

  // ---- hoisted layer-1 B fragments ----
  bf16x8 bf1r[8][2];
  #pragma unroll
  for (int ks = 0; ks < 8; ++ks) {
    int kb = ks * 4 + wq;
    bf1r[ks][0] = __builtin_bit_cast(bf16x8, *(const int4*)(Bp1 + ((size_t)kb * 128 + c0) * 8));
    bf1r[ks][1] = __builtin_bit_cast(bf16x8, *(const int4*)(Bp1 + ((size_t)kb * 128 + c1) * 8));
  }

  // ---- gather: async global->LDS, linear dest, pre-swizzled source ----
  #pragma unroll
  for (int it = 0; it < 8; ++it) {
    int seg = it * 16 + s0;
    int r = seg >> 1;
    int gs = g ^ (r & 7);
    const unsigned short* src = xb + (size_t)idxv[it] * 128 + gs * 8;
    char* dstbase = Alds + (it * 16 + wave * 4) * 256;
    __builtin_amdgcn_global_load_lds((g_u32*)(void*)src, (l_u32*)(void*)dstbase, 16, 0, 0);
  }
  __syncthreads();

  // ---- layer 1 accumulator init: b1 + edge_attr x W1[0:4] in fp32 ----
  f32x4 acc[4][2];
  #pragma unroll
  for (int mf = 0; mf < 4; ++mf)
    #pragma unroll
    for (int rg = 0; rg < 4; ++rg) {
      int r = mf * 16 + wq * 4 + rg;
      float e0 = ealds[r * 4 + 0], e1 = ealds[r * 4 + 1];
      float e2 = ealds[r * 4 + 2], e3 = ealds[r * 4 + 3];
      acc[mf][0][rg] = bias0 + e0 * w00 + e1 * w01 + e2 * w02 + e3 * w03;
      acc[mf][1][rg] = bias1 + e0 * w10 + e1 * w11 + e2 * w12 + e3 * w13;
    }

  // ---- layer 1 MFMA: K = 256 (sender 128 | receiver 128) ----
  #pragma unroll
  for (int ks = 0; ks < 8; ++ks) {
    #pragma unroll
    for (int mf = 0; mf < 4; ++mf) {
      int r = mf * 16 + l16;
      int lofs = (r * 512 + ks * 64 + wq * 16) ^ ((r & 7) << 4);
      bf16x8 av = __builtin_bit_cast(bf16x8, *(const int4*)(Alds + lofs));
      acc[mf][0] = __builtin_amdgcn_mfma_f32_16x16x32_bf16(av, bf1r[ks][0], acc[mf][0], 0, 0, 0);
      acc[mf][1] = __builtin_amdgcn_mfma_f32_16x16x32_bf16(av, bf1r[ks][1], acc[mf][1], 0, 0, 0);
    }
  }

  // ---- layer-2 B fragments: issue now, latency hides under barriers/H-write ----
  bf16x8 bf2r[4][2];
  #pragma unroll
  for (int ks = 0; ks < 4; ++ks) {
    int kb = ks * 4 + wq;
    bf2r[ks][0] = __builtin_bit_cast(bf16x8, *(const int4*)(Bp2 + ((size_t)kb * 128 + c0) * 8));
    bf2r[ks][1] = __builtin_bit_cast(bf16x8, *(const int4*)(Bp2 + ((size_t)kb * 128 + c1) * 8));
  }

  // BAR2: all waves done reading A-tile -> safe to overlay H
  __syncthreads();

  // ---- ReLU + h -> LDS (bf16, swizzled), overlaid into A-tile ----
  #pragma unroll
  for (int mf = 0; mf < 4; ++mf)
    #pragma unroll
    for (int nf = 0; nf < 2; ++nf) {
      int c = wave * 32 + nf * 16 + l16;
      #pragma unroll
      for (int rg = 0; rg < 4; ++rg) {
        int r = mf * 16 + wq * 4 + rg;
        float v = fmaxf(acc[mf][nf][rg], 0.0f);
        int lofs = (r * 256 + c * 2) ^ ((r & 7) << 4);
        *(unsigned short*)(Hlds + lofs) = f2bf(v);
      }
    }
  // BAR3: H visible
  __syncthreads();

  // ---- layer 2: K = 128 ----
  f32x4 acc2[4][2];
  #pragma unroll
  for (int mf = 0; mf < 4; ++mf) {
    acc2[mf][0] = (f32x4){bias20, bias20, bias20, bias20};
    acc2[mf][1] = (f32x4){bias21, bias21, bias21, bias21};
  }
  #pragma unroll
  for (int ks = 0; ks < 4; ++ks) {
    #pragma unroll
    for (int mf = 0; mf < 4; ++mf) {
      int r = mf * 16 + l16;
      int lofs = (r * 256 + ks * 64 + wq * 16) ^ ((r & 7) << 4);
      bf16x8 av = __builtin_bit_cast(bf16x8, *(const int4*)(Hlds + lofs));
      acc2[mf][0] = __builtin_amdgcn_mfma_f32_16x16x32_bf16(av, bf2r[ks][0], acc2[mf][0], 0, 0, 0);
      acc2[mf][1] = __builtin_amdgcn_mfma_f32_16x16x32_bf16(av, bf2r[ks][1], acc2[mf][1], 0, 0, 0);
    }
  }

  // ---- epilogue: scalar stores, consecutive lanes -> consecutive addresses ----
  #pragma unroll
  for (int mf = 0; mf < 4; ++mf)
    #pragma unroll
    for (int nf = 0; nf < 2; ++nf) {
      int c = wave * 32 + nf * 16 + l16;
      #pragma unroll
      for (int rg = 0; rg < 4; ++rg) {
        int r = mf * 16 + wq * 4 + rg;
        outp[(size_t)(eb + r) * 128 + c] = acc2[mf][nf][rg];
      }
    }
}

// ---------------- fallback (fp32 gather, non-persistent) for small ws ----------------
__global__ __launch_bounds__(256, 3)
void edge_main_f32(const float* __restrict__ xf,
                   const float* __restrict__ ea, const int* __restrict__ eidx,
                   const float* __restrict__ W1, const float* __restrict__ b1,
                   const float* __restrict__ b2,
                   const unsigned short* __restrict__ Bp1, const unsigned short* __restrict__ Bp2,
                   float* __restrict__ outp, int E) {
  __shared__ int4 AldsV[2048];
  __shared__ int4 HldsV[1024];
  __shared__ float ealds[256];
  char* Alds = (char*)AldsV;
  char* Hlds = (char*)HldsV;

  const int tid  = threadIdx.x;
  const int lane = tid & 63;
  const int wq   = lane >> 4;
  const int l16  = lane & 15;
  const int wave = tid >> 6;
  const int eb   = blockIdx.x * BM;

  ealds[tid] = ea[eb * 4 + tid];

  const int g  = tid & 15;
  const int s0 = tid >> 4;

  int idxv[8];
  #pragma unroll
  for (int it = 0; it < 8; ++it) {
    int seg = it * 16 + s0;
    idxv[it] = eidx[(seg & 1) * E + eb + (seg >> 1)];
  }

  const int c0 = wave * 32 + l16;
  const int c1 = c0 + 16;
  const float bias0 = b1[c0], bias1 = b1[c1];
  const float w00 = W1[c0],       w01 = W1[128 + c0], w02 = W1[256 + c0], w03 = W1[384 + c0];
  const float w10 = W1[c1],       w11 = W1[128 + c1], w12 = W1[256 + c1], w13 = W1[384 + c1];
  const float bias20 = b2[c0], bias21 = b2[c1];

  bf16x8 bf1r[8][2];
  #pragma unroll
  for (int ks = 0; ks < 8; ++ks) {
    int kb = ks * 4 + wq;
    bf1r[ks][0] = __builtin_bit_cast(bf16x8, *(const int4*)(Bp1 + ((size_t)kb * 128 + c0) * 8));
    bf1r[ks][1] = __builtin_bit_cast(bf16x8, *(const int4*)(Bp1 + ((size_t)kb * 128 + c1) * 8));
  }

  #pragma unroll
  for (int it = 0; it < 8; ++it) {
    int seg = it * 16 + s0;
    int r = seg >> 1, half = seg & 1;
    int lofs = (r * 512 + half * 256 + g * 16) ^ ((r & 7) << 4);
    const float* src = xf + (size_t)idxv[it] * 128 + g * 8;
    float4 a = *(const float4*)src;
    float4 c = *(const float4*)(src + 4);
    unsigned short h[8] = {f2bf(a.x), f2bf(a.y), f2bf(a.z), f2bf(a.w),
                           f2bf(c.x), f2bf(c.y), f2bf(c.z), f2bf(c.w)};
    int4 pk; __builtin_memcpy(&pk, h, 16);
    *(int4*)(Alds + lofs) = pk;
  }
  __syncthreads();

  f32x4 acc[4][2];
  #pragma unroll
  for (int mf = 0; mf < 4; ++mf)
    #pragma unroll
    for (int rg = 0; rg < 4; ++rg) {
      int r = mf * 16 + wq * 4 + rg;
      float e0 = ealds[r * 4 + 0], e1 = ealds[r * 4 + 1];
      float e2 = ealds[r * 4 + 2], e3 = ealds[r * 4 + 3];
      acc[mf][0][rg] = bias0 + e0 * w00 + e1 * w01 + e2 * w02 + e3 * w03;
      acc[mf][1][rg] = bias1 + e0 * w10 + e1 * w11 + e2 * w12 + e3 * w13;
    }

  #pragma unroll
  for (int ks = 0; ks < 8; ++ks)
    #pragma unroll
    for (int mf = 0; mf < 4; ++mf) {
      int r = mf * 16 + l16;
      int lofs = (r * 512 + ks * 64 + wq * 16) ^ ((r & 7) << 4);
      bf16x8 av = __builtin_bit_cast(bf16x8, *(const int4*)(Alds + lofs));
      acc[mf][0] = __builtin_amdgcn_mfma_f32_16x16x32_bf16(av, bf1r[ks][0], acc[mf][0], 0, 0, 0);
      acc[mf][1] = __builtin_amdgcn_mfma_f32_16x16x32_bf16(av, bf1r[ks][1], acc[mf][1], 0, 0, 0);
    }

  bf16x8 bf2r[4][2];
  #pragma unroll
  for (int ks = 0; ks < 4; ++ks) {
    int kb = ks * 4 + wq;
    bf2r[ks][0] = __builtin_bit_cast(bf16x8, *(const int4*)(Bp2 + ((size_t)kb * 128 + c0) * 8));
    bf2r[ks][1] = __builtin_bit_cast(bf16x8, *(const int4*)(Bp2 + ((size_t)kb * 128 + c1) * 8));
  }

  #pragma unroll
  for (int mf = 0; mf < 4; ++mf)
    #pragma unroll
    for (int nf = 0; nf < 2; ++nf) {
      int c = wave * 32 + nf * 16 + l16;
      #pragma unroll
      for (int rg = 0; rg < 4; ++rg) {
        int r = mf * 16 + wq * 4 + rg;
        float v = fmaxf(acc[mf][nf][rg], 0.0f);
        int lofs = (r * 256 + c * 2) ^ ((r & 7) << 4);
        *(unsigned short*)(Hlds + lofs) = f2bf(v);
      }
    }
  __syncthreads();

  f32x4 acc2[4][2];
  #pragma unroll
  for (int mf = 0; mf < 4; ++mf) {
    acc2[mf][0] = (f32x4){bias20, bias20, bias20, bias20};
    acc2[mf][1] = (f32x4){bias21, bias21, bias21, bias21};
  }
  #pragma unroll
  for (int ks = 0; ks < 4; ++ks)
    #pragma unroll
    for (int mf = 0; mf < 4; ++mf) {
      int r = mf * 16 + l16;
      int lofs = (r * 256 + ks * 64 + wq * 16) ^ ((r & 7) << 4);
      bf16x8 av = __builtin_bit_cast(bf16x8, *(const int4*)(Hlds + lofs));
      acc2[mf][0] = __builtin_amdgcn_mfma_f32_16x16x32_bf16(av, bf2r[ks][0], acc2[mf][0], 0, 0, 0);
      acc2[mf][1] = __builtin_amdgcn_mfma_f32_16x16x32_bf16(av, bf2r[ks][1], acc2[mf][1], 0, 0, 0);
    }

  #pragma unroll
  for (int mf = 0; mf < 4; ++mf)
    #pragma unroll
    for (int nf = 0; nf < 2; ++nf) {
      int c = wave * 32 + nf * 16 + l16;
      #pragma unroll
      for (int rg = 0; rg < 4; ++rg) {
        int r = mf * 16 + wq * 4 + rg;
        outp[(size_t)(eb + r) * 128 + c] = acc2[mf][nf][rg];
      }
    }
}

extern "C" void kernel_launch(void* const* d_in, const int* in_sizes, int n_in,
                              void* d_out, int out_size, void* d_ws, size_t ws_size,
                              hipStream_t stream) {
  const float* x  = (const float*)d_in[0];
  const float* ea = (const float*)d_in[1];
  const int* eidx = (const int*)d_in[2];
  const float* W1 = (const float*)d_in[3];
  const float* b1 = (const float*)d_in[4];
  const float* W2 = (const float*)d_in[5];
  const float* b2 = (const float*)d_in[6];
  float* outp = (float*)d_out;

  const int E = in_sizes[2] / 2;
  const int nnodes = in_sizes[0] / 128;
  const int ntiles = E / BM;

  unsigned short* Bp1 = (unsigned short*)d_ws;           // 64 KB
  unsigned short* Bp2 = Bp1 + 32768;                     // 32 KB
  unsigned short* xb  = (unsigned short*)((char*)d_ws + 98304);
  const size_t need = 98304 + (size_t)nnodes * 128 * 2;

  pack_w_kernel<<<192, 256, 0, stream>>>(W1, W2, Bp1, Bp2);

  if (ws_size >= need) {
    int n8 = nnodes * 128 / 8;
    convert_x_kernel<<<(n8 + 255) / 256, 256, 0, stream>>>(x, xb, n8);
    edge_tile2<<<ntiles, 256, 0, stream>>>(xb, ea, eidx, W1, b1, b2, Bp1, Bp2, outp, E);
  } else {
    edge_main_f32<<<ntiles, 256, 0, stream>>>(x, ea, eidx, W1, b1, b2, Bp1, Bp2, outp, E);
  }
}